// Round 6
// baseline (325.355 us; speedup 1.0000x reference)
//
#include <hip/hip_runtime.h>
#include <hip/hip_bf16.h>
#include <math.h>

#define BATCH 4
#define SEQ   2048
#define DM    512
#define NH    8
#define DK    64
#define FF    2048
#define BT    (BATCH * SEQ)   // 8192

// q pre-scale: 0.125 * log2(e)  -> softmax uses exp2 directly
#define SCALE_Q 0.18033688011112042f

typedef short bf16x8 __attribute__((ext_vector_type(8)));
typedef float f32x4  __attribute__((ext_vector_type(4)));

static __device__ inline short f2bf(float f) {
  union { float f; unsigned u; } v; v.f = f;
  unsigned r = (v.u + 0x7fffu + ((v.u >> 16) & 1u)) >> 16;
  return (short)r;
}

// async 16B global->LDS (gfx950). LDS dest = wave-uniform base + lane*16.
static __device__ __forceinline__ void gload16(const short* g, short* l) {
  __builtin_amdgcn_global_load_lds(
      (const __attribute__((address_space(1))) void*)g,
      (__attribute__((address_space(3))) void*)l, 16, 0, 0);
}

// ---------------------------------------------------------------------------
// LayerNorm: one block per row of 512, fp32 in -> bf16 out
// ---------------------------------------------------------------------------
__global__ __launch_bounds__(256) void ln_kernel(
    const float* __restrict__ x, const float* __restrict__ gamma,
    const float* __restrict__ beta, short* __restrict__ out) {
  int row = blockIdx.x;
  const float* xr = x + (size_t)row * DM;
  int t = threadIdx.x;
  float v0 = xr[t], v1 = xr[t + 256];
  float s = v0 + v1;
  float sq = v0 * v0 + v1 * v1;
  for (int off = 32; off; off >>= 1) {
    s  += __shfl_xor(s, off);
    sq += __shfl_xor(sq, off);
  }
  __shared__ float ssum[4], ssq[4];
  int wave = t >> 6, lane = t & 63;
  if (lane == 0) { ssum[wave] = s; ssq[wave] = sq; }
  __syncthreads();
  if (t == 0) {
    float S = ssum[0] + ssum[1] + ssum[2] + ssum[3];
    float Q = ssq[0] + ssq[1] + ssq[2] + ssq[3];
    float mu = S * (1.0f / DM);
    float var = Q * (1.0f / DM) - mu * mu;
    ssum[0] = mu;
    ssq[0] = rsqrtf(var + 1e-5f);
  }
  __syncthreads();
  float mu = ssum[0], rstd = ssq[0];
  short* orow = out + (size_t)row * DM;
  orow[t]       = f2bf((v0 - mu) * rstd * gamma[t]       + beta[t]);
  orow[t + 256] = f2bf((v1 - mu) * rstd * gamma[t + 256] + beta[t + 256]);
}

// ---------------------------------------------------------------------------
// Weight convert+transpose fp32 [R][C] -> bf16 [C][R].
// ---------------------------------------------------------------------------
__global__ __launch_bounds__(256) void wconv_kernel(
    const float* Wq, const float* Wk, const float* Wv,
    const float* Wp, const float* W1, const float* W2,
    short* wqkv, short* wpt, short* w1t, short* w2t) {
  int z = blockIdx.z;
  const float* src; short* dst; int R, C;
  if (z < 24) {
    int m = z >> 3, hh = z & 7;
    const float* s0 = (m == 0) ? Wq : (m == 1) ? Wk : Wv;
    src = s0 + (size_t)hh * 512 * 64;
    dst = wqkv + ((size_t)(m * 512 + hh * 64)) * 512;
    R = 512; C = 64;
  } else if (z == 24) { src = Wp; dst = wpt; R = 512;  C = 512;  }
  else if (z == 25)   { src = W1; dst = w1t; R = 512;  C = 2048; }
  else                { src = W2; dst = w2t; R = 2048; C = 512;  }
  int tx = blockIdx.x, ty = blockIdx.y;
  if (tx >= C / 64 || ty >= R / 64) return;
  __shared__ float Ts[64][68];
  int t = threadIdx.x;
  int r = t >> 2, c0 = (t & 3) * 16;
  const float* sp = src + (size_t)(ty * 64 + r) * C + tx * 64 + c0;
#pragma unroll
  for (int i = 0; i < 16; i += 4) {
    float4 v = *(const float4*)(sp + i);
    Ts[c0 + i + 0][r] = v.x; Ts[c0 + i + 1][r] = v.y;
    Ts[c0 + i + 2][r] = v.z; Ts[c0 + i + 3][r] = v.w;
  }
  __syncthreads();
  short* dp = dst + (size_t)(tx * 64 + r) * R + ty * 64 + c0;
  short tmp[16];
#pragma unroll
  for (int i = 0; i < 16; ++i) tmp[i] = f2bf(Ts[r][c0 + i]);
  *(int4*)(dp)     = *(int4*)&tmp[0];
  *(int4*)(dp + 8) = *(int4*)&tmp[8];
}

// ---------------------------------------------------------------------------
// GEMM core, async-staged + XOR-swizzled LDS.
// Tile TM x 128, BK=64. LDS: As[TM][64], Bs[128][64] (unpadded, 16B-chunk
// swizzle: logical chunk l of row r lives at physical chunk l^(r&7)).
// Frag reads hit 8 distinct bank groups x2 lanes = free 2-way.
// ---------------------------------------------------------------------------
template<int TM>
__device__ __forceinline__ void gemm_core(
    const short* __restrict__ A, const short* __restrict__ Bw,
    int m0, int n0, int K, short* smem, f32x4 (&acc)[TM / 32][4]) {
  constexpr int AF = TM / 32;
  constexpr int AC = TM / 32;          // A staging calls (TM*8/256)
  short* As = smem;
  short* Bs = smem + TM * 64;
  int t = threadIdx.x;
  int wave = t >> 6, lane = t & 63, quad = lane >> 4, l16 = lane & 15;
  int wr = wave >> 1, wc = wave & 1;

  size_t aoff[AC]; size_t boff[4];
  short* alds[AC]; short* blds[4];
#pragma unroll
  for (int c = 0; c < AC; ++c) {
    int p = c * 256 + t, row = p >> 3, lg = (p & 7) ^ (row & 7);
    aoff[c] = (size_t)(m0 + row) * K + lg * 8;
    alds[c] = As + c * 2048 + wave * 512;
  }
#pragma unroll
  for (int c = 0; c < 4; ++c) {
    int p = c * 256 + t, row = p >> 3, lg = (p & 7) ^ (row & 7);
    boff[c] = (size_t)(n0 + row) * K + lg * 8;
    blds[c] = Bs + c * 2048 + wave * 512;
  }

  int swz = (l16 & 7);
  for (int k0 = 0; k0 < K; k0 += 64) {
    __syncthreads();
#pragma unroll
    for (int c = 0; c < AC; ++c) gload16(A + aoff[c] + k0, alds[c]);
#pragma unroll
    for (int c = 0; c < 4; ++c) gload16(Bw + boff[c] + k0, blds[c]);
    __syncthreads();
#pragma unroll
    for (int kk = 0; kk < 2; ++kk) {
      int phys = ((kk * 4 + quad) ^ swz) * 8;
      bf16x8 af[AF], bfr[4];
#pragma unroll
      for (int i = 0; i < AF; ++i)
        af[i] = *(const bf16x8*)&As[(wr * (TM / 2) + i * 16 + l16) * 64 + phys];
#pragma unroll
      for (int j = 0; j < 4; ++j)
        bfr[j] = *(const bf16x8*)&Bs[(wc * 64 + j * 16 + l16) * 64 + phys];
#pragma unroll
      for (int i = 0; i < AF; ++i)
#pragma unroll
        for (int j = 0; j < 4; ++j)
          acc[i][j] = __builtin_amdgcn_mfma_f32_16x16x32_bf16(af[i], bfr[j], acc[i][j], 0, 0, 0);
    }
  }
}

template<int TM>
__global__ __launch_bounds__(256) void mgemm_kernel(
    const short* __restrict__ A, const short* __restrict__ Bw,
    const float* __restrict__ bias, const float* __restrict__ res,
    void* __restrict__ C, int N, int K, int dorelu, int bf16out) {
  __shared__ __align__(16) short smem[TM * 64 + 128 * 64];
  f32x4 acc[TM / 32][4];
  f32x4 zf = {0.f, 0.f, 0.f, 0.f};
#pragma unroll
  for (int i = 0; i < TM / 32; ++i)
#pragma unroll
    for (int j = 0; j < 4; ++j) acc[i][j] = zf;
  int m0 = blockIdx.y * TM, n0 = blockIdx.x * 128;
  gemm_core<TM>(A, Bw, m0, n0, K, smem, acc);

  int t = threadIdx.x;
  int wave = t >> 6, lane = t & 63, quad = lane >> 4, l16 = lane & 15;
  int wr = wave >> 1, wc = wave & 1;
#pragma unroll
  for (int i = 0; i < TM / 32; ++i) {
    int rl = m0 + wr * (TM / 2) + i * 16 + quad * 4;
#pragma unroll
    for (int j = 0; j < 4; ++j) {
      int nc = n0 + wc * 64 + j * 16 + l16;
      float bv = bias[nc];
#pragma unroll
      for (int r = 0; r < 4; ++r) {
        float v = acc[i][j][r] + bv;
        if (dorelu) v = fmaxf(v, 0.0f);
        size_t off = (size_t)(rl + r) * N + nc;
        if (res) v += res[off];
        if (bf16out) ((short*)C)[off] = f2bf(v);
        else         ((float*)C)[off] = v;
      }
    }
  }
}

// ---------------------------------------------------------------------------
// Fused QKV GEMM (q scaled by SCALE_Q; v written transposed per-head)
// ---------------------------------------------------------------------------
__global__ __launch_bounds__(256) void qkv_kernel(
    const short* __restrict__ A, const short* __restrict__ Bw,
    const float* __restrict__ bq, const float* __restrict__ bk,
    const float* __restrict__ bv,
    short* __restrict__ q, short* __restrict__ k, short* __restrict__ vt) {
  __shared__ __align__(16) short smem[17408];  // >= 16384 core, = 128*136 Ts
  f32x4 acc[4][4];
  f32x4 zf = {0.f, 0.f, 0.f, 0.f};
#pragma unroll
  for (int i = 0; i < 4; ++i)
#pragma unroll
    for (int j = 0; j < 4; ++j) acc[i][j] = zf;
  int m0 = blockIdx.y * 128, n0 = blockIdx.x * 128;
  gemm_core<128>(A, Bw, m0, n0, DM, smem, acc);

  int t = threadIdx.x;
  int wave = t >> 6, lane = t & 63, quad = lane >> 4, l16 = lane & 15;
  int wr = wave >> 1, wc = wave & 1;

  if (n0 < 1024) {
    short* out = (n0 < 512) ? q : k;
    const float* bias = (n0 < 512) ? bq + n0 : bk + (n0 - 512);
    float scale = (n0 < 512) ? SCALE_Q : 1.0f;
    int ncol0 = (n0 < 512) ? n0 : n0 - 512;
#pragma unroll
    for (int i = 0; i < 4; ++i) {
      int rl = m0 + wr * 64 + i * 16 + quad * 4;
#pragma unroll
      for (int j = 0; j < 4; ++j) {
        int ncl = wc * 64 + j * 16 + l16;
        float bvv = bias[ncl];
#pragma unroll
        for (int r = 0; r < 4; ++r) {
          float v = (acc[i][j][r] + bvv) * scale;
          out[(size_t)(rl + r) * DM + ncol0 + ncl] = f2bf(v);
        }
      }
    }
  } else {
    const float* bias = bv + (n0 - 1024);
    __syncthreads();
    short* Ts = smem;  // [128][136]
#pragma unroll
    for (int i = 0; i < 4; ++i) {
      int rl = wr * 64 + i * 16 + quad * 4;
#pragma unroll
      for (int j = 0; j < 4; ++j) {
        int cl = wc * 64 + j * 16 + l16;
        float bvv = bias[cl];
#pragma unroll
        for (int r = 0; r < 4; ++r)
          Ts[cl * 136 + rl + r] = f2bf(acc[i][j][r] + bvv);
      }
    }
    __syncthreads();
    int nl = t >> 1, half = (t & 1) * 64;
    int gn = (n0 - 1024) + nl;
    int hh = gn >> 6, dk = gn & 63;
    int bidx = m0 >> 11, s0 = (m0 & 2047) + half;
    short* dst = vt + ((size_t)((bidx * NH + hh) * DK + dk)) * SEQ + s0;
    const short* srcT = &Ts[nl * 136 + half];
#pragma unroll
    for (int i2 = 0; i2 < 64; i2 += 8)
      *(int4*)(dst + i2) = *(const int4*)(srcT + i2);
  }
}

// ---------------------------------------------------------------------------
// Flash attention v4: async-staged swizzled K/V tiles, no-max softmax with
// exp2 (q pre-scaled by 0.125*log2e), S^T layout (lane-local l), 128-key
// tiles. grid (SEQ/128, NH, B). Masked p = 0 (== exp(-1.25e8) in fp32).
// ---------------------------------------------------------------------------
__global__ __launch_bounds__(256) void fattn_kernel(
    const short* __restrict__ Q, const short* __restrict__ Kg,
    const short* __restrict__ Vt, short* __restrict__ O) {
  int qb = gridDim.x - 1 - blockIdx.x;  // heavy tiles dispatch first
  int h = blockIdx.y, b = blockIdx.z;
  int q0 = qb * 128;
  int t = threadIdx.x, wave = t >> 6, lane = t & 63, quad = lane >> 4, l16 = lane & 15;
  __shared__ __align__(16) short Ks[128 * 64];    // [key][dk], 8-chunk swizzle
  __shared__ __align__(16) short Vs[64 * 128];    // [dk][key], 16-chunk swizzle
  __shared__ __align__(16) short Ps[4][16 * 136]; // per-wave P [qrow][key]

  f32x4 zf = {0.f, 0.f, 0.f, 0.f};
  bf16x8 qf[2][2];
#pragma unroll
  for (int f = 0; f < 2; ++f) {
    const short* qp = Q + ((size_t)(b * SEQ + q0 + f * 64 + wave * 16 + l16)) * DM + h * DK;
    qf[f][0] = *(const bf16x8*)(qp + quad * 8);
    qf[f][1] = *(const bf16x8*)(qp + 32 + quad * 8);
  }

  f32x4 o_acc[2][4];
  float l_part[2] = {0.0f, 0.0f};
#pragma unroll
  for (int f = 0; f < 2; ++f)
#pragma unroll
    for (int j = 0; j < 4; ++j) o_acc[f][j] = zf;

  // staging descriptors
  const short* kbase = Kg + ((size_t)(b * SEQ)) * DM + h * DK;
  const short* vbase = Vt + ((size_t)((b * NH + h) * DK)) * SEQ;
  size_t koff[4], voff[4];
  short *klds[4], *vlds[4];
#pragma unroll
  for (int c = 0; c < 4; ++c) {
    int p = c * 256 + t;
    int krow = p >> 3, klg = (p & 7) ^ (krow & 7);
    koff[c] = (size_t)krow * DM + klg * 8;
    klds[c] = Ks + c * 2048 + wave * 512;
    int vrow = p >> 4, vlg = (p & 15) ^ (vrow & 15);
    voff[c] = (size_t)vrow * SEQ + vlg * 8;
    vlds[c] = Vs + c * 2048 + wave * 512;
  }
  int swz8 = l16 & 7;

  for (int kt = 0; kt <= qb; ++kt) {
    __syncthreads();
#pragma unroll
    for (int c = 0; c < 4; ++c) gload16(kbase + koff[c] + (size_t)kt * 128 * DM, klds[c]);
#pragma unroll
    for (int c = 0; c < 4; ++c) gload16(vbase + voff[c] + kt * 128, vlds[c]);
    __syncthreads();
    bool diag = (kt == qb);

    bf16x8 apf[2][4];
#pragma unroll
    for (int f = 0; f < 2; ++f) {
      int rb = q0 + f * 64 + wave * 16;
      // S^T: key = nt*16+quad*4+r, qrow = rb+l16
      f32x4 sf[8];
#pragma unroll
      for (int nt = 0; nt < 8; ++nt) {
        bf16x8 ka0 = *(const bf16x8*)&Ks[(nt * 16 + l16) * 64 + ((0 ^ swz8) ^ quad ^ 0) * 8 + ((quad ^ swz8) - (quad ^ swz8)) ];
        // (clean form below; the compiler folds both to the same address)
        ka0 = *(const bf16x8*)&Ks[(nt * 16 + l16) * 64 + ((quad) ^ swz8) * 8];
        bf16x8 ka1 = *(const bf16x8*)&Ks[(nt * 16 + l16) * 64 + ((4 + quad) ^ swz8) * 8];
        f32x4 s = zf;
        s = __builtin_amdgcn_mfma_f32_16x16x32_bf16(ka0, qf[f][0], s, 0, 0, 0);
        s = __builtin_amdgcn_mfma_f32_16x16x32_bf16(ka1, qf[f][1], s, 0, 0, 0);
        sf[nt] = s;
      }
      int qrow = rb + l16;
      float lp = 0.0f;
#pragma unroll
      for (int nt = 0; nt < 8; ++nt) {
        short tmp[4];
        if (diag) {
          int keyb = kt * 128 + nt * 16 + quad * 4;
#pragma unroll
          for (int r = 0; r < 4; ++r) {
            float p = (keyb + r > qrow) ? 0.0f : exp2f(sf[nt][r]);
            lp += p;
            tmp[r] = f2bf(p);
          }
        } else {
#pragma unroll
          for (int r = 0; r < 4; ++r) {
            float p = exp2f(sf[nt][r]);
            lp += p;
            tmp[r] = f2bf(p);
          }
        }
        *(int2*)&Ps[wave][l16 * 136 + nt * 16 + quad * 4] = *(int2*)tmp;
      }
      l_part[f] += lp;
#pragma unroll
      for (int kc = 0; kc < 4; ++kc)
        apf[f][kc] = *(const bf16x8*)&Ps[wave][l16 * 136 + kc * 32 + quad * 8];
    }

    // O += P V  (V-frags shared across both row-frags)
#pragma unroll
    for (int nt2 = 0; nt2 < 4; ++nt2) {
#pragma unroll
      for (int kc = 0; kc < 4; ++kc) {
        int vrow = nt2 * 16 + l16;
        bf16x8 vf = *(const bf16x8*)&Vs[vrow * 128 + (((kc * 4 + quad) ^ (vrow & 15))) * 8];
        o_acc[0][nt2] = __builtin_amdgcn_mfma_f32_16x16x32_bf16(apf[0][kc], vf, o_acc[0][nt2], 0, 0, 0);
        o_acc[1][nt2] = __builtin_amdgcn_mfma_f32_16x16x32_bf16(apf[1][kc], vf, o_acc[1][nt2], 0, 0, 0);
      }
    }
  }

#pragma unroll
  for (int f = 0; f < 2; ++f) {
    float lf = l_part[f];
    lf += __shfl_xor(lf, 16);
    lf += __shfl_xor(lf, 32);   // lanes sharing l16 now hold full l[qrow]
    int rb = q0 + f * 64 + wave * 16;
#pragma unroll
    for (int r = 0; r < 4; ++r) {
      float lv = __shfl(lf, quad * 4 + r);
      float inv = 1.0f / lv;
      int row = rb + quad * 4 + r;
#pragma unroll
      for (int nt2 = 0; nt2 < 4; ++nt2)
        O[((size_t)(b * SEQ) + row) * DM + h * DK + nt2 * 16 + l16] =
            f2bf(o_acc[f][nt2][r] * inv);
    }
  }
}

// ---------------------------------------------------------------------------
extern "C" void kernel_launch(void* const* d_in, const int* in_sizes, int n_in,
                              void* d_out, int out_size, void* d_ws, size_t ws_size,
                              hipStream_t stream) {
  const float* x   = (const float*)d_in[0];
  const float* Wq  = (const float*)d_in[1];
  const float* bq  = (const float*)d_in[2];
  const float* Wk  = (const float*)d_in[3];
  const float* bk  = (const float*)d_in[4];
  const float* Wv  = (const float*)d_in[5];
  const float* bv  = (const float*)d_in[6];
  const float* Wp  = (const float*)d_in[7];
  const float* bp  = (const float*)d_in[8];
  const float* W1  = (const float*)d_in[9];
  const float* b1  = (const float*)d_in[10];
  const float* W2  = (const float*)d_in[11];
  const float* b2  = (const float*)d_in[12];
  const float* g1  = (const float*)d_in[13];
  const float* be1 = (const float*)d_in[14];
  const float* g2  = (const float*)d_in[15];
  const float* be2 = (const float*)d_in[16];
  float* out = (float*)d_out;

  char* wsb = (char*)d_ws;
  const size_t SB = (size_t)BT * DM * 2;  // 8 MB
  short* h    = (short*)(wsb);
  short* q    = (short*)(wsb + SB);
  short* k    = (short*)(wsb + 2 * SB);
  short* vt   = (short*)(wsb + 3 * SB);
  short* o    = (short*)(wsb + 4 * SB);
  float* x2   = (float*)(wsb + 5 * SB);                       // 16 MB
  short* h2   = (short*)(wsb + 5 * SB + (size_t)BT * DM * 4);
  short* ff   = (short*)(wsb + 6 * SB + (size_t)BT * DM * 4); // 32 MB
  short* wqkv = (short*)(wsb + 6 * SB + (size_t)BT * DM * 4 + (size_t)BT * FF * 2);
  short* wpt  = wqkv + 1536 * 512;
  short* w1t  = wpt + 512 * 512;
  short* w2t  = w1t + 2048 * 512;

  dim3 blk(256);

  wconv_kernel<<<dim3(32, 32, 27), blk, 0, stream>>>(Wq, Wk, Wv, Wp, W1, W2,
                                                     wqkv, wpt, w1t, w2t);
  ln_kernel<<<BT, blk, 0, stream>>>(x, g1, be1, h);

  qkv_kernel<<<dim3(12, 64), blk, 0, stream>>>(h, wqkv, bq, bk, bv, q, k, vt);

  fattn_kernel<<<dim3(SEQ / 128, NH, BATCH), blk, 0, stream>>>(q, k, vt, o);

  mgemm_kernel<64><<<dim3(4, 128), blk, 0, stream>>>(o, wpt, bp, x, x2, DM, DM, 0, 0);
  ln_kernel<<<BT, blk, 0, stream>>>(x2, g2, be2, h2);
  mgemm_kernel<128><<<dim3(16, 64), blk, 0, stream>>>(h2, w1t, b1, nullptr, ff, FF, DM, 1, 1);
  mgemm_kernel<64><<<dim3(4, 128), blk, 0, stream>>>(ff, w2t, b2, x2, out, DM, FF, 0, 0);
}